// Round 10
// baseline (341.609 us; speedup 1.0000x reference)
//
#include <hip/hip_runtime.h>

// LSTM, barrier-free per-wave MFMA formulation. Round 16: R13 dataflow +
// cell-split tile order + software-pipelined exp2 + sched_group_barrier
// choreography. B=4096, T=512, I=10, H=32, O=1. Gates i,f,g,o.
//
// R15 post-mortem: bpermute h-ring regressed (261us, 8.4M DS conflicts) ->
// LDS ring restored. R13 budget: serial ring ~520 cyc/step (ds_read 60 +
// MFMA pipe 310 + drain 20 + exp2 16 + combine 80 + pack/write 30) but
// measured window 1070 -> ~550 cyc of scheduling slack (MfmaUtil 25 +
// VALU 50 + 25% stall; compiler clusters MFMAs away from act VALU).
//
// R16 forces the interleave, same 16 MFMAs (structurally minimal: useful
// K-slots = 10 + 32 + 22 = 64 = 2xK32):
//  (a) cell-split order: tiles 0,2,4,6 (cell0 gates i,f,g,o) first ->
//      cell0's exp2/combine/h-write overlap cell1's tiles 1,3,5,7.
//  (b) each exp2 textually 2 MFMA-pairs after its producer (drained).
//  (c) sched_group_barrier {DS_READ 2, VALU 14, 8x{MFMA 2, VALU 3}} pins
//      the pattern (T19 recipe); branchless x-refill keeps one BB.
//
// Mappings (verified R3-R13): A row m = L (batch L>>2, dup-4), A[m][k=8Q+j];
// C col=L, row=4Q+reg, reg0 of quad Q = batch Q. Act: lane (Q,L) owns batch
// Q, hids {L(cell0), L+16(cell1)}; cell0 = even tiles, cell1 = odd.
// Merged-K (R9): MFMA1 A={x_hat k0..9 | h_lo k10..31}, MFMA2 A=h_hi.
// Shared-denominator act (R13): 5 exp2 + 3 rcp per cell. fp16 2-term h
// split, lo dropped ch0..9 (absmax 2e-3 verified). LDS h ring, no barriers.
//
// Grid: 1024 blocks x 64 threads (1 wave/block = 1/SIMD), 4 batches/wave,
// launch_bounds(64,1).

#define T_SZ 512
#define I_SZ 10
#define H_SZ 32

typedef _Float16 half8  __attribute__((ext_vector_type(8)));
typedef __fp16   fp16x2 __attribute__((ext_vector_type(2)));
typedef float    f32x4  __attribute__((ext_vector_type(4)));
typedef int      i32x4  __attribute__((ext_vector_type(4)));

union FH { i32x4 i; half8 h; };
static __device__ __forceinline__ half8 fragv(i32x4 v) { FH u; u.i = v; return u.h; }
static __device__ __forceinline__ half8 frag4(int a, int b, int c, int d) {
    FH u; u.i = (i32x4){a, b, c, d}; return u.h;
}

// pack 2 fp32 -> 2 fp16 in one dword (v_cvt_pkrtz_f16_f32)
static __device__ __forceinline__ int pk16(float lo, float hi) {
    union { fp16x2 h; int i; } u;
    u.h = __builtin_amdgcn_cvt_pkrtz(lo, hi);
    return u.i;
}

#define MFMAH(A, B, C) __builtin_amdgcn_mfma_f32_16x16x32_f16((A), (B), (C), 0, 0, 0)
#define EXP2(x) __builtin_amdgcn_exp2f(x)
#define RCP(x)  __builtin_amdgcn_rcpf(x)
#define SGB(m, n) __builtin_amdgcn_sched_group_barrier((m), (n), 0)

__global__ __launch_bounds__(64, 1)
void lstm_wave(const float* __restrict__ x, const float* __restrict__ W_ih,
               const float* __restrict__ W_hh, const float* __restrict__ b_ih,
               const float* __restrict__ b_hh, const float* __restrict__ W_dense,
               const float* __restrict__ b_dense, float* __restrict__ out)
{
    const int lane  = threadIdx.x;        // 0..63 (block = one wave)
    const int L     = lane & 15;          // A m-row / C col
    const int Q     = lane >> 4;          // k-quad / C row-quad (= act batch)
    const int bbase = blockIdx.x * 4;     // 1024 blocks x 4 batches

    const int bA = L >> 2;                // A-side batch (4 dup rows per batch)
    const int h0 = L, h1 = L + 16;        // this lane's two hidden channels

    // ---- B-fragments for all 8 tiles (one-time) ----
    // tile tau = 2*gate + hhalf: W row = 32*gate + 16*hhalf + L
    int bhh[8][4];
    int bm[8][4];
    #pragma unroll
    for (int tau = 0; tau < 8; ++tau) {
        const int wr = 32 * (tau >> 1) + 16 * (tau & 1) + L;
        const float* ph = W_hh + wr * H_SZ + 8 * Q;
        #pragma unroll
        for (int d = 0; d < 4; ++d) {
            float2 v = *(const float2*)(ph + 2 * d);
            bhh[tau][d] = pk16(v.x, v.y);
        }
        if (Q == 0) {
            const float* pi = W_ih + wr * I_SZ;       // k0..7 = W_ih cols 0..7
            #pragma unroll
            for (int d = 0; d < 4; ++d) {
                float2 v = *(const float2*)(pi + 2 * d);
                bm[tau][d] = pk16(v.x, v.y);
            }
        } else if (Q == 1) {
            // k8,9 = W_ih cols 8,9; k10..15 = W_hh cols 10..15
            float2 v = *(const float2*)(W_ih + wr * I_SZ + 8);
            bm[tau][0] = pk16(v.x, v.y);
            #pragma unroll
            for (int d = 1; d < 4; ++d) {
                float2 w = *(const float2*)(W_hh + wr * H_SZ + 8 + 2 * d);
                bm[tau][d] = pk16(w.x, w.y);
            }
        } else {
            bm[tau][0] = bhh[tau][0]; bm[tau][1] = bhh[tau][1];
            bm[tau][2] = bhh[tau][2]; bm[tau][3] = bhh[tau][3];
        }
    }

    // ---- biases folded into exp2 args; per gate, both cells ----
    const float nL = -1.4426950f;     // -log2(e)       (sigmoid)
    const float m2 = -2.8853901f;     // -2*log2(e)     (tanh via (1-D)/(1+D))
    float mb0[4], mb1[4];             // gate order i,f,g,o
    #pragma unroll
    for (int gt = 0; gt < 4; ++gt) {
        const float sc = (gt == 2) ? m2 : nL;
        mb0[gt] = sc * (b_ih[32 * gt + h0] + b_hh[32 * gt + h0]);
        mb1[gt] = sc * (b_ih[32 * gt + h1] + b_hh[32 * gt + h1]);
    }

    // ---- per-wave LDS h buffer: [buf][plane hi/lo][batch 0..3][hid] fp16 ----
    __shared__ __attribute__((aligned(16))) _Float16 hbuf[2][2][4][H_SZ];  // 1 KiB
    {
        int* zz = (int*)&hbuf[0][0][0][0];
        zz[lane] = 0; zz[lane + 64] = 0; zz[lane + 128] = 0; zz[lane + 192] = 0;
    }
    // wave-ordered DS: zeros visible to this wave's later reads, no barrier.

    // ---- x stream: 2-deep prefetch (each lane loads its A-side batch row) ----
    const float* xrow = x + (size_t)(bbase + bA) * (T_SZ * I_SZ);
    float2 xa0 = *(const float2*)(xrow + 0), xa1 = *(const float2*)(xrow + 2),
           xa2 = *(const float2*)(xrow + 4), xa3 = *(const float2*)(xrow + 6),
           xa4 = *(const float2*)(xrow + 8);
    float2 xb0 = *(const float2*)(xrow + I_SZ + 0), xb1 = *(const float2*)(xrow + I_SZ + 2),
           xb2 = *(const float2*)(xrow + I_SZ + 4), xb3 = *(const float2*)(xrow + I_SZ + 6),
           xb4 = *(const float2*)(xrow + I_SZ + 8);

    const f32x4 zerov = {0.f, 0.f, 0.f, 0.f};
    float cst0 = 0.0f, cst1 = 0.0f;
    float h0last = 0.0f, h1last = 0.0f;
    const bool q0 = (Q == 0), q1 = (Q == 1);

    for (int t = 0; t < T_SZ; t += 2) {
        #pragma unroll
        for (int u = 0; u < 2; ++u) {
            const int rb = u, wb = u ^ 1;

            // ---- h fragments from private LDS (A-frag order, broadcast) ----
            i32x4 hhi_ = *(const i32x4*)&hbuf[rb][0][bA][8 * Q];
            i32x4 lo_  = *(const i32x4*)&hbuf[rb][1][bA][8 * Q];

            // x_hat packs (u is compile-time; selects fold away)
            float2 y0 = u ? xb0 : xa0, y1 = u ? xb1 : xa1, y2 = u ? xb2 : xa2,
                   y3 = u ? xb3 : xa3, y4 = u ? xb4 : xa4;
            int p0 = pk16(y0.x, y0.y), p1 = pk16(y1.x, y1.y), p2 = pk16(y2.x, y2.y),
                p3 = pk16(y3.x, y3.y), p4 = pk16(y4.x, y4.y);

            // merged A-frag: k0..9 = x_hat, k10..31 = h_lo channels 10..31
            half8 mf = fragv((i32x4){ q0 ? p0 : (q1 ? p4 : lo_[0]),
                                      q0 ? p1 : lo_[1],
                                      q0 ? p2 : lo_[2],
                                      q0 ? p3 : lo_[3] });
            half8 hhi = fragv(hhi_);

            // branchless x-refill (always in-bounds; garbage unused at tail)
            {
                int tt = t + 2 + u; tt = (tt < T_SZ - 1) ? tt : (T_SZ - 1);
                const float* xr = xrow + tt * I_SZ;
                if (u == 0) {
                    xa0 = *(const float2*)(xr + 0); xa1 = *(const float2*)(xr + 2);
                    xa2 = *(const float2*)(xr + 4); xa3 = *(const float2*)(xr + 6);
                    xa4 = *(const float2*)(xr + 8);
                } else {
                    xb0 = *(const float2*)(xr + 0); xb1 = *(const float2*)(xr + 2);
                    xb2 = *(const float2*)(xr + 4); xb3 = *(const float2*)(xr + 6);
                    xb4 = *(const float2*)(xr + 8);
                }
            }

            // ---- cell0 tiles (0,2,4,6) first; exp2 pipelined 2 pairs back ---
            f32x4 a0 = MFMAH(mf,  frag4(bm[0][0],  bm[0][1],  bm[0][2],  bm[0][3]),  zerov);
            a0       = MFMAH(hhi, frag4(bhh[0][0], bhh[0][1], bhh[0][2], bhh[0][3]), a0);
            f32x4 a2 = MFMAH(mf,  frag4(bm[2][0],  bm[2][1],  bm[2][2],  bm[2][3]),  zerov);
            a2       = MFMAH(hhi, frag4(bhh[2][0], bhh[2][1], bhh[2][2], bhh[2][3]), a2);
            float eI0 = EXP2(fmaf(nL, a0[0], mb0[0]));
            f32x4 a4 = MFMAH(mf,  frag4(bm[4][0],  bm[4][1],  bm[4][2],  bm[4][3]),  zerov);
            a4       = MFMAH(hhi, frag4(bhh[4][0], bhh[4][1], bhh[4][2], bhh[4][3]), a4);
            float eF0 = EXP2(fmaf(nL, a2[0], mb0[1]));
            f32x4 a6 = MFMAH(mf,  frag4(bm[6][0],  bm[6][1],  bm[6][2],  bm[6][3]),  zerov);
            a6       = MFMAH(hhi, frag4(bhh[6][0], bhh[6][1], bhh[6][2], bhh[6][3]), a6);
            float eG0 = EXP2(fmaf(m2, a4[0], mb0[2]));

            // ---- cell1 tiles (1,3,5,7); cell0 combine runs underneath ----
            f32x4 a1 = MFMAH(mf,  frag4(bm[1][0],  bm[1][1],  bm[1][2],  bm[1][3]),  zerov);
            a1       = MFMAH(hhi, frag4(bhh[1][0], bhh[1][1], bhh[1][2], bhh[1][3]), a1);
            float eO0 = EXP2(fmaf(nL, a6[0], mb0[3]));
            float fg0 = RCP(1.0f + eF0);
            f32x4 a3 = MFMAH(mf,  frag4(bm[3][0],  bm[3][1],  bm[3][2],  bm[3][3]),  zerov);
            a3       = MFMAH(hhi, frag4(bhh[3][0], bhh[3][1], bhh[3][2], bhh[3][3]), a3);
            float igg0 = (1.0f - eG0) * RCP((1.0f + eI0) * (1.0f + eG0));
            cst0 = fmaf(fg0, cst0, igg0);
            f32x4 a5 = MFMAH(mf,  frag4(bm[5][0],  bm[5][1],  bm[5][2],  bm[5][3]),  zerov);
            a5       = MFMAH(hhi, frag4(bhh[5][0], bhh[5][1], bhh[5][2], bhh[5][3]), a5);
            float eI1 = EXP2(fmaf(nL, a1[0], mb1[0]));
            float eD0 = EXP2(m2 * cst0);
            f32x4 a7 = MFMAH(mf,  frag4(bm[7][0],  bm[7][1],  bm[7][2],  bm[7][3]),  zerov);
            a7       = MFMAH(hhi, frag4(bhh[7][0], bhh[7][1], bhh[7][2], bhh[7][3]), a7);
            float eF1 = EXP2(fmaf(nL, a3[0], mb1[1]));
            float hv0 = (1.0f - eD0) * RCP((1.0f + eO0) * (1.0f + eD0));
            h0last = hv0;
            // write cell0's h immediately (feeds next step's Q0/Q1 reads)
            {
                _Float16 hh = (_Float16)hv0;
                _Float16 hl = (_Float16)(hv0 - (float)hh);
                hbuf[wb][0][Q][h0] = hh;
                hbuf[wb][1][Q][h0] = hl;
            }

            // ---- tail: cell1 act ----
            float eG1 = EXP2(fmaf(m2, a5[0], mb1[2]));
            float eO1 = EXP2(fmaf(nL, a7[0], mb1[3]));
            float fg1  = RCP(1.0f + eF1);
            float igg1 = (1.0f - eG1) * RCP((1.0f + eI1) * (1.0f + eG1));
            cst1 = fmaf(fg1, cst1, igg1);
            float eD1 = EXP2(m2 * cst1);
            float hv1 = (1.0f - eD1) * RCP((1.0f + eO1) * (1.0f + eD1));
            h1last = hv1;
            {
                _Float16 hh = (_Float16)hv1;
                _Float16 hl = (_Float16)(hv1 - (float)hh);
                hbuf[wb][0][Q][h1] = hh;
                hbuf[wb][1][Q][h1] = hl;
            }
            // wave-ordered DS: next iteration's reads see these writes.

            // ---- schedule choreography (T19): pin the interleave ----
            // {2 ds_read, 14 VALU (packs/sels), 8x{2 MFMA, 3 VALU}}; tail free
            SGB(0x100, 2);            // DS_READ
            SGB(0x002, 14);           // VALU: x-pack + frag selects
            SGB(0x008, 2); SGB(0x002, 3);
            SGB(0x008, 2); SGB(0x002, 3);
            SGB(0x008, 2); SGB(0x002, 3);
            SGB(0x008, 2); SGB(0x002, 3);
            SGB(0x008, 2); SGB(0x002, 3);
            SGB(0x008, 2); SGB(0x002, 3);
            SGB(0x008, 2); SGB(0x002, 3);
            SGB(0x008, 2); SGB(0x002, 3);
        }
    }

    // ---- dense head: out[b] = h . W_dense + b_dense ----
    // lane (Q,L) holds hids {L, L+16} of batch Q; reduce over the 16-lane quad
    float v = h0last * W_dense[h0] + h1last * W_dense[h1];
    #pragma unroll
    for (int m = 8; m >= 1; m >>= 1)
        v += __shfl_xor(v, m);            // reduce within each 16-lane quad
    if (L == 0) out[bbase + Q] = v + b_dense[0];
}

extern "C" void kernel_launch(void* const* d_in, const int* in_sizes, int n_in,
                              void* d_out, int out_size, void* d_ws, size_t ws_size,
                              hipStream_t stream) {
    const float* x       = (const float*)d_in[0];
    const float* W_ih    = (const float*)d_in[1];
    const float* W_hh    = (const float*)d_in[2];
    const float* b_ih    = (const float*)d_in[3];
    const float* b_hh    = (const float*)d_in[4];
    const float* W_dense = (const float*)d_in[5];
    const float* b_dense = (const float*)d_in[6];
    float* out = (float*)d_out;

    // 1024 blocks x 64 threads = 1024 independent waves (1/SIMD), 4 batches each
    lstm_wave<<<dim3(1024), dim3(64), 0, stream>>>(
        x, W_ih, W_hh, b_ih, b_hh, W_dense, b_dense, out);
}

// Round 11
// 333.295 us; speedup vs baseline: 1.0249x; 1.0249x over previous
//
#include <hip/hip_runtime.h>

// LSTM, barrier-free per-wave MFMA formulation. Round 17: 2 waves/SIMD with
// forced anti-phase. B=4096, T=512, I=10, H=32, O=1. Gates i,f,g,o.
//
// R16 post-mortem: SGB choreography regressed (256us, VALUBusy 50->36:
// pinned pattern inserted bubbles). R13 (237us) = reference.
//
// R13 decomposition: window 1070 = issue ~470 (trans 256 + MFMA 64 + VALU
// 120 + DS 30) + ~400-500 dependency stall (h ds_read latency, exp2/rcp
// chains, MFMA drain). Within-wave stall-filling failed 4x (R11/R14/R15/
// R16). R17 fills stalls with a SECOND co-resident wave per SIMD:
//   - 2048 blocks x 64 thr, launch_bounds(64,2): 2 waves/SIMD.
//   - per wave: 2 batches dup-8 (R9-verified mapping), 16 MFMAs/step ->
//     per-SIMD MFMA pipe 600 cyc/4 batches < R13's 1070 window: pipe not
//     binding if overlap engages.
//   - act: R13 shared-denominator, 1 cell/lane (5 exp2 + 3 rcp).
//   - anti-phase forcing: (1) one-time s_sleep(8) (~512 cyc) on blocks with
//     (blockIdx>>10)&1 — SIMD-mates are n, n+1024 under round-robin fill;
//     (2) s_setprio(1) around the MFMA region (T5: pays when co-resident
//     waves sit at different phases) so the MFMA-phase wave wins issue
//     while its partner runs act VALU. Contention repels re-alignment.
//
// K-packing (R9 merged-K, verified): per tile MFMA1 A={x_hat k0..9 |
// h_lo k10..31}, MFMA2 A=h_hi k0..31; B-frags bm/bhh as R13. fp16 2-term
// h split, lo dropped ch0..9 (absmax 2e-3). Biases folded into exp2 args.
// h ring through private per-wave LDS (wave-ordered DS, no barriers).
//
// Mappings (R9-verified): A row m = L, batch = L>>3 (dup-8), A[m][k=8Q+j];
// C col=L, row=4Q+reg; keep reg 0: row 4Q -> batch Q>>1. Act: lane (Q,L)
// owns (batch Q>>1, hid L+16*(Q&1)); gates = v[2g + (Q&1)].

#define T_SZ 512
#define I_SZ 10
#define H_SZ 32

typedef _Float16 half8  __attribute__((ext_vector_type(8)));
typedef __fp16   fp16x2 __attribute__((ext_vector_type(2)));
typedef float    f32x4  __attribute__((ext_vector_type(4)));
typedef int      i32x4  __attribute__((ext_vector_type(4)));

union FH { i32x4 i; half8 h; };
static __device__ __forceinline__ half8 fragv(i32x4 v) { FH u; u.i = v; return u.h; }
static __device__ __forceinline__ half8 frag4(int a, int b, int c, int d) {
    FH u; u.i = (i32x4){a, b, c, d}; return u.h;
}

// pack 2 fp32 -> 2 fp16 in one dword (v_cvt_pkrtz_f16_f32)
static __device__ __forceinline__ int pk16(float lo, float hi) {
    union { fp16x2 h; int i; } u;
    u.h = __builtin_amdgcn_cvt_pkrtz(lo, hi);
    return u.i;
}

#define MFMAH(A, B, C) __builtin_amdgcn_mfma_f32_16x16x32_f16((A), (B), (C), 0, 0, 0)
#define EXP2(x) __builtin_amdgcn_exp2f(x)
#define RCP(x)  __builtin_amdgcn_rcpf(x)

__global__ __launch_bounds__(64, 2)
void lstm_wave(const float* __restrict__ x, const float* __restrict__ W_ih,
               const float* __restrict__ W_hh, const float* __restrict__ b_ih,
               const float* __restrict__ b_hh, const float* __restrict__ W_dense,
               const float* __restrict__ b_dense, float* __restrict__ out)
{
    const int lane  = threadIdx.x;        // 0..63 (block = one wave)
    const int L     = lane & 15;          // A m-row / C col
    const int Q     = lane >> 4;          // k-quad
    const int bbase = blockIdx.x * 2;     // 2048 blocks x 2 batches

    const int bA   = L >> 3;              // A-side batch (dup-8)
    const int bAct = Q >> 1;              // act-side batch
    const int hidA = L + 16 * (Q & 1);    // act-side hidden index

    // ---- B-fragments for all 8 tiles (one-time) ----
    // tile tau = 2*gate + hhalf: W row = 32*gate + 16*hhalf + L
    int bhh[8][4];
    int bm[8][4];
    #pragma unroll
    for (int tau = 0; tau < 8; ++tau) {
        const int wr = 32 * (tau >> 1) + 16 * (tau & 1) + L;
        const float* ph = W_hh + wr * H_SZ + 8 * Q;
        #pragma unroll
        for (int d = 0; d < 4; ++d) {
            float2 v = *(const float2*)(ph + 2 * d);
            bhh[tau][d] = pk16(v.x, v.y);
        }
        if (Q == 0) {
            const float* pi = W_ih + wr * I_SZ;       // k0..7 = W_ih cols 0..7
            #pragma unroll
            for (int d = 0; d < 4; ++d) {
                float2 v = *(const float2*)(pi + 2 * d);
                bm[tau][d] = pk16(v.x, v.y);
            }
        } else if (Q == 1) {
            // k8,9 = W_ih cols 8,9; k10..15 = W_hh cols 10..15
            float2 v = *(const float2*)(W_ih + wr * I_SZ + 8);
            bm[tau][0] = pk16(v.x, v.y);
            #pragma unroll
            for (int d = 1; d < 4; ++d) {
                float2 w = *(const float2*)(W_hh + wr * H_SZ + 8 + 2 * d);
                bm[tau][d] = pk16(w.x, w.y);
            }
        } else {
            bm[tau][0] = bhh[tau][0]; bm[tau][1] = bhh[tau][1];
            bm[tau][2] = bhh[tau][2]; bm[tau][3] = bhh[tau][3];
        }
    }

    // ---- biases folded into exp2 args (this lane's single cell) ----
    const float nL = -1.4426950f;     // -log2(e)       (sigmoid)
    const float m2 = -2.8853901f;     // -2*log2(e)     (tanh via (1-D)/(1+D))
    const float mbi = nL * (b_ih[hidA]      + b_hh[hidA]);
    const float mbf = nL * (b_ih[32 + hidA] + b_hh[32 + hidA]);
    const float mbg = m2 * (b_ih[64 + hidA] + b_hh[64 + hidA]);
    const float mbo = nL * (b_ih[96 + hidA] + b_hh[96 + hidA]);

    // ---- per-wave LDS h buffer: [buf][plane hi/lo][batch 0..1][hid] fp16 ----
    __shared__ __attribute__((aligned(16))) _Float16 hbuf[2][2][2][H_SZ];  // 512 B
    {
        int* zz = (int*)&hbuf[0][0][0][0];
        zz[lane] = 0;                 // 128 ints total
        zz[lane + 64] = 0;
    }
    // wave-ordered DS: zeros visible to this wave's later reads, no barrier.

    // ---- x stream: 2-deep prefetch (each lane loads its A-side batch row) ----
    const float* xrow = x + (size_t)(bbase + bA) * (T_SZ * I_SZ);
    float2 xa0 = *(const float2*)(xrow + 0), xa1 = *(const float2*)(xrow + 2),
           xa2 = *(const float2*)(xrow + 4), xa3 = *(const float2*)(xrow + 6),
           xa4 = *(const float2*)(xrow + 8);
    float2 xb0 = *(const float2*)(xrow + I_SZ + 0), xb1 = *(const float2*)(xrow + I_SZ + 2),
           xb2 = *(const float2*)(xrow + I_SZ + 4), xb3 = *(const float2*)(xrow + I_SZ + 6),
           xb4 = *(const float2*)(xrow + I_SZ + 8);

    const f32x4 zerov = {0.f, 0.f, 0.f, 0.f};
    float cst = 0.0f;
    float hlast = 0.0f;
    const bool q0 = (Q == 0), q1 = (Q == 1);
    const bool qh = (Q & 1);

    // ---- anti-phase stagger: SIMD-mates are blocks n and n+1024 under
    // round-robin fill; offset the second cohort by ~half a step window ----
    if ((blockIdx.x >> 10) & 1)
        __builtin_amdgcn_s_sleep(8);      // ~512 cycles

    for (int t = 0; t < T_SZ; t += 2) {
        #pragma unroll
        for (int u = 0; u < 2; ++u) {
            const int rb = u, wb = u ^ 1;

            // h fragments from private LDS (A-frag order, broadcast reads)
            i32x4 hhi_ = *(const i32x4*)&hbuf[rb][0][bA][8 * Q];
            i32x4 lo_  = *(const i32x4*)&hbuf[rb][1][bA][8 * Q];

            // x_hat packs (u is compile-time; selects fold away)
            float2 y0 = u ? xb0 : xa0, y1 = u ? xb1 : xa1, y2 = u ? xb2 : xa2,
                   y3 = u ? xb3 : xa3, y4 = u ? xb4 : xa4;
            int p0 = pk16(y0.x, y0.y), p1 = pk16(y1.x, y1.y), p2 = pk16(y2.x, y2.y),
                p3 = pk16(y3.x, y3.y), p4 = pk16(y4.x, y4.y);

            // merged A-frag: k0..9 = x_hat, k10..31 = h_lo channels 10..31
            half8 mf = fragv((i32x4){ q0 ? p0 : (q1 ? p4 : lo_[0]),
                                      q0 ? p1 : lo_[1],
                                      q0 ? p2 : lo_[2],
                                      q0 ? p3 : lo_[3] });
            half8 hhi = fragv(hhi_);

            // ---- MFMA region (prio 1): gate tile-pairs + this cell's exp2 ----
            __builtin_amdgcn_s_setprio(1);
            f32x4 a0 = MFMAH(mf,  frag4(bm[0][0],  bm[0][1],  bm[0][2],  bm[0][3]),  zerov);
            a0       = MFMAH(hhi, frag4(bhh[0][0], bhh[0][1], bhh[0][2], bhh[0][3]), a0);
            f32x4 a1 = MFMAH(mf,  frag4(bm[1][0],  bm[1][1],  bm[1][2],  bm[1][3]),  zerov);
            a1       = MFMAH(hhi, frag4(bhh[1][0], bhh[1][1], bhh[1][2], bhh[1][3]), a1);
            float eA = EXP2(fmaf(nL, qh ? a1[0] : a0[0], mbi));

            f32x4 a2 = MFMAH(mf,  frag4(bm[2][0],  bm[2][1],  bm[2][2],  bm[2][3]),  zerov);
            a2       = MFMAH(hhi, frag4(bhh[2][0], bhh[2][1], bhh[2][2], bhh[2][3]), a2);
            f32x4 a3 = MFMAH(mf,  frag4(bm[3][0],  bm[3][1],  bm[3][2],  bm[3][3]),  zerov);
            a3       = MFMAH(hhi, frag4(bhh[3][0], bhh[3][1], bhh[3][2], bhh[3][3]), a3);
            float eF = EXP2(fmaf(nL, qh ? a3[0] : a2[0], mbf));

            f32x4 a4 = MFMAH(mf,  frag4(bm[4][0],  bm[4][1],  bm[4][2],  bm[4][3]),  zerov);
            a4       = MFMAH(hhi, frag4(bhh[4][0], bhh[4][1], bhh[4][2], bhh[4][3]), a4);
            f32x4 a5 = MFMAH(mf,  frag4(bm[5][0],  bm[5][1],  bm[5][2],  bm[5][3]),  zerov);
            a5       = MFMAH(hhi, frag4(bhh[5][0], bhh[5][1], bhh[5][2], bhh[5][3]), a5);
            float eG = EXP2(fmaf(m2, qh ? a5[0] : a4[0], mbg));

            f32x4 a6 = MFMAH(mf,  frag4(bm[6][0],  bm[6][1],  bm[6][2],  bm[6][3]),  zerov);
            a6       = MFMAH(hhi, frag4(bhh[6][0], bhh[6][1], bhh[6][2], bhh[6][3]), a6);
            f32x4 a7 = MFMAH(mf,  frag4(bm[7][0],  bm[7][1],  bm[7][2],  bm[7][3]),  zerov);
            a7       = MFMAH(hhi, frag4(bhh[7][0], bhh[7][1], bhh[7][2], bhh[7][3]), a7);
            __builtin_amdgcn_s_setprio(0);
            float eO = EXP2(fmaf(nL, qh ? a7[0] : a6[0], mbo));

            // refill consumed x set from t+2+u (loads fly under the combines)
            if (t + 2 + u < T_SZ) {
                const float* xr = xrow + (t + 2 + u) * I_SZ;
                if (u == 0) {
                    xa0 = *(const float2*)(xr + 0); xa1 = *(const float2*)(xr + 2);
                    xa2 = *(const float2*)(xr + 4); xa3 = *(const float2*)(xr + 6);
                    xa4 = *(const float2*)(xr + 8);
                } else {
                    xb0 = *(const float2*)(xr + 0); xb1 = *(const float2*)(xr + 2);
                    xb2 = *(const float2*)(xr + 4); xb3 = *(const float2*)(xr + 6);
                    xb4 = *(const float2*)(xr + 8);
                }
            }

            // ---- combine (shared-denominator gates, 3 rcp) ----
            // i*g~ = (1-B)/((1+A)(1+B)); f = 1/(1+F); h = (1-D)/((1+O)(1+D))
            float fg  = RCP(1.0f + eF);
            float igg = (1.0f - eG) * RCP((1.0f + eA) * (1.0f + eG));
            cst = fmaf(fg, cst, igg);
            float eD = EXP2(m2 * cst);
            float hv = (1.0f - eD) * RCP((1.0f + eO) * (1.0f + eD));
            hlast = hv;

            // h write-back, fp16 2-term split, [plane][batch][hid] layout
            _Float16 hh = (_Float16)hv;
            _Float16 hl = (_Float16)(hv - (float)hh);
            hbuf[wb][0][bAct][hidA] = hh;
            hbuf[wb][1][bAct][hidA] = hl;
            // wave-ordered DS: next iteration's reads see these writes.
        }
    }

    // ---- dense head: out[b] = h . W_dense + b_dense ----
    // batch 0 lives in lanes 0-31 (Q=0,1), batch 1 in lanes 32-63 (Q=2,3)
    float v = hlast * W_dense[hidA];
    #pragma unroll
    for (int m = 16; m >= 1; m >>= 1)
        v += __shfl_xor(v, m);            // reduce within 32-lane halves
    if (lane == 0)  out[bbase + 0] = v + b_dense[0];
    if (lane == 32) out[bbase + 1] = v + b_dense[0];
}

extern "C" void kernel_launch(void* const* d_in, const int* in_sizes, int n_in,
                              void* d_out, int out_size, void* d_ws, size_t ws_size,
                              hipStream_t stream) {
    const float* x       = (const float*)d_in[0];
    const float* W_ih    = (const float*)d_in[1];
    const float* W_hh    = (const float*)d_in[2];
    const float* b_ih    = (const float*)d_in[3];
    const float* b_hh    = (const float*)d_in[4];
    const float* W_dense = (const float*)d_in[5];
    const float* b_dense = (const float*)d_in[6];
    float* out = (float*)d_out;

    // 2048 blocks x 64 threads = 2 waves/SIMD, 2 batches/wave, anti-phased
    lstm_wave<<<dim3(2048), dim3(64), 0, stream>>>(
        x, W_ih, W_hh, b_ih, b_hh, W_dense, b_dense, out);
}